// Round 12
// baseline (2098.339 us; speedup 1.0000x reference)
//
#include <hip/hip_runtime.h>
#include <math.h>

namespace {
constexpr int B_ = 64, T_ = 12, N_ = 1024, H_ = 64, E_ = 16;
constexpr int C_  = 65;          // DIN + H
constexpr int BC_ = B_ * C_;     // 4160
constexpr int OG_ = 128;         // gate output = 2H
constexpr int OU_ = 64;          // update output = H
constexpr float EPS_ = 1e-12f;
constexpr int KP_ = 224;         // packed contract K: 3*65=195 + pad to 7*32
constexpr int COLG_ = OG_ * KP_; // 28672
constexpr int COLU_ = OU_ * KP_; // 14336
constexpr int NE_ = N_ * E_;     // 16384
}

typedef unsigned short u16;
typedef unsigned int u32;
using f16x8 = __attribute__((ext_vector_type(8))) _Float16;
using f16x4 = __attribute__((ext_vector_type(4))) _Float16;
using f32x4 = __attribute__((ext_vector_type(4))) float;

__device__ __forceinline__ u32 div65(u32 x) { return (x * 16135u) >> 20; }  // exact for x<5196

// async global->LDS 16B/lane; LDS dest is wave-uniform base + lane*16.
__device__ __forceinline__ void gl_lds16(const void* g, void* l, int lane) {
#if __has_builtin(__builtin_amdgcn_global_load_lds)
  __builtin_amdgcn_global_load_lds((const __attribute__((address_space(1))) u32*)g,
                                   (__attribute__((address_space(3))) u32*)l, 16, 0, 0);
#else
  *(uint4*)((char*)l + lane * 16) = *(const uint4*)g;
#endif
}

// ---------------------------------------------------------------------------
// device bodies shared by fused kernels
// ---------------------------------------------------------------------------
__device__ __forceinline__ void wprep_body(const float* __restrict__ wp, int NO,
                                           _Float16* __restrict__ wpC, int k, int tid) {
  if (tid >= NO) return;
  f16x8 lo = {}, hi = {};
  if (k < 195) {
    const u32 seg = div65((u32)k);
    const u32 ii = k - seg * 65;
#pragma unroll
    for (int d = 0; d < 8; d++)
      lo[d] = (_Float16)wp[(((size_t)d * 3 + seg) * 65 + ii) * NO + tid];
#pragma unroll
    for (int d = 0; d < 8; d++)
      hi[d] = (_Float16)wp[(((size_t)(d + 8) * 3 + seg) * 65 + ii) * NO + tid];
  }
  _Float16* dst = &wpC[((size_t)tid * KP_ + k) * 16];
  *(f16x8*)dst = lo;
  *(f16x8*)(dst + 8) = hi;
}

__device__ __forceinline__ void sup_body(const float* __restrict__ eT,
                                         _Float16* __restrict__ s16,
                                         int n, int tid, float* red) {
  float en[E_];
#pragma unroll
  for (int d = 0; d < E_; d++) en[d] = eT[d * N_ + n];
  float lg[4];
  float mx = -3.4e38f;
#pragma unroll
  for (int j = 0; j < 4; j++) {
    int m = tid + 256 * j;
    float s = 0.f;
#pragma unroll
    for (int d = 0; d < E_; d++) s = fmaf(en[d], eT[d * N_ + m], s);
    lg[j] = s;
    mx = fmaxf(mx, s);
  }
  red[tid] = mx; __syncthreads();
  for (int off = 128; off > 0; off >>= 1) {
    if (tid < off) red[tid] = fmaxf(red[tid], red[tid + off]);
    __syncthreads();
  }
  mx = red[0]; __syncthreads();
  float sum = 0.f;
#pragma unroll
  for (int j = 0; j < 4; j++) { lg[j] = __expf(lg[j] - mx); sum += lg[j]; }
  red[tid] = sum; __syncthreads();
  for (int off = 128; off > 0; off >>= 1) {
    if (tid < off) red[tid] += red[tid + off];
    __syncthreads();
  }
  float inv = 1.0f / red[0];
#pragma unroll
  for (int j = 0; j < 4; j++)
    s16[(size_t)n * N_ + tid + 256 * j] = (_Float16)(lg[j] * inv);
}

__device__ __forceinline__ void wgen_body(const float* __restrict__ e,
                                          const _Float16* __restrict__ wpC, int COLS,
                                          _Float16* __restrict__ Wt,
                                          int xb, int yb, int tid, float (*es)[16]) {
  const int col0 = xb * 1024 + tid * 4;
  const int n0 = yb * 64;
#pragma unroll
  for (int q = 0; q < 4; q++) {
    int idx = tid + q * 256;
    es[idx >> 4][idx & 15] = e[(size_t)n0 * 16 + idx];
  }
  __syncthreads();
  float wc[4][16];
#pragma unroll
  for (int cc = 0; cc < 4; cc++) {
    f16x8 a = *(const f16x8*)&wpC[(size_t)(col0 + cc) * 16];
    f16x8 b = *(const f16x8*)&wpC[(size_t)(col0 + cc) * 16 + 8];
#pragma unroll
    for (int d = 0; d < 8; d++) { wc[cc][d] = (float)a[d]; wc[cc][8 + d] = (float)b[d]; }
  }
  for (int nn = 0; nn < 64; nn++) {
    float acc[4] = {};
#pragma unroll
    for (int d = 0; d < 16; d++) {
      float ev = es[nn][d];
#pragma unroll
      for (int cc = 0; cc < 4; cc++) acc[cc] = fmaf(ev, wc[cc][d], acc[cc]);
    }
    f16x4 pv;
#pragma unroll
    for (int cc = 0; cc < 4; cc++) pv[cc] = (_Float16)acc[cc];
    *(f16x4*)&Wt[(size_t)(n0 + nn) * COLS + col0] = pv;
  }
}

// 64x64 fp16 transpose tile: ST[m][n] = S[n][m].
__device__ __forceinline__ void supT_body(const _Float16* __restrict__ S,
                                          _Float16* __restrict__ ST,
                                          int tile, int tid, _Float16 (*lds)[66]) {
  const int n0 = (tile >> 4) * 64;
  const int m0 = (tile & 15) * 64;
  {
    const int r = tid >> 2, c0 = (tid & 3) * 16;
    const _Float16* sp = &S[(size_t)(n0 + r) * 1024 + m0 + c0];
    f16x8 a = *(const f16x8*)sp;
    f16x8 b = *(const f16x8*)(sp + 8);
#pragma unroll
    for (int i = 0; i < 8; i++) { lds[r][c0 + i] = a[i]; lds[r][c0 + 8 + i] = b[i]; }
  }
  __syncthreads();
  {
    const int c = tid >> 2, r0 = (tid & 3) * 16;
    f16x8 a, b;
#pragma unroll
    for (int i = 0; i < 8; i++) { a[i] = lds[r0 + i][c]; b[i] = lds[r0 + 8 + i][c]; }
    _Float16* dp = &ST[(size_t)(m0 + c) * 1024 + n0 + r0];
    *(f16x8*)dp = a;
    *(f16x8*)(dp + 8) = b;
  }
}

// ---------------------------------------------------------------------------
// Single-A GEMM body (used for sup2 = sup @ supT), rowout mode.
__device__ __forceinline__ void gemm_body(
    const _Float16* __restrict__ A, const _Float16* __restrict__ Bt,
    _Float16* __restrict__ rowout,
    int bx, int by, int tid, _Float16* As, _Float16* Bs) {
  const int wave = tid >> 6, lane = tid & 63;
  const int m0 = by * 128, c0 = bx * 64;
  const int lrow = lane >> 3;
  const int lchunk = lane & 7;
  const int fm = lane & 15, fq = lane >> 4;
  f32x4 acc[2][4] = {};
  for (int ks = 0; ks < 16; ks++) {
    const int kp = ks * 64;
#pragma unroll
    for (int q = 0; q < 4; q++) {
      const int seg = wave * 4 + q;
      const int row = seg * 8 + lrow;
      const int sw = lchunk ^ (row & 7);
      gl_lds16(A + (size_t)(m0 + row) * 1024 + kp + sw * 8, &As[seg * 8 * 64], lane);
    }
#pragma unroll
    for (int q = 0; q < 2; q++) {
      const int seg = wave * 2 + q;
      const int row = seg * 8 + lrow;
      const int sw = lchunk ^ (row & 7);
      gl_lds16(Bt + (size_t)(c0 + row) * 1024 + kp + sw * 8, &Bs[seg * 8 * 64], lane);
    }
    __syncthreads();
#pragma unroll
    for (int kk = 0; kk < 2; kk++) {
      f16x8 af[2], bfr[4];
      const int g = kk * 4 + fq;
#pragma unroll
      for (int mt = 0; mt < 2; mt++) {
        const int row = wave * 32 + mt * 16 + fm;
        af[mt] = *(const f16x8*)&As[row * 64 + (g ^ (row & 7)) * 8];
      }
#pragma unroll
      for (int nt = 0; nt < 4; nt++) {
        const int row = nt * 16 + fm;
        bfr[nt] = *(const f16x8*)&Bs[row * 64 + (g ^ (row & 7)) * 8];
      }
#pragma unroll
      for (int mt = 0; mt < 2; mt++)
#pragma unroll
        for (int nt = 0; nt < 4; nt++)
          acc[mt][nt] = __builtin_amdgcn_mfma_f32_16x16x32_f16(af[mt], bfr[nt], acc[mt][nt], 0, 0, 0);
    }
    __syncthreads();
  }
  const int q4 = fq * 4;
#pragma unroll
  for (int nt = 0; nt < 4; nt++) {
    const int col = c0 + nt * 16 + fm;
#pragma unroll
    for (int mt = 0; mt < 2; mt++) {
      const int row = m0 + wave * 32 + mt * 16 + q4;
      const f32x4 v = acc[mt][nt];
#pragma unroll
      for (int j = 0; j < 4; j++)
        rowout[(size_t)(row + j) * 1024 + col] = (_Float16)v[j];
    }
  }
}

// ---------------------------------------------------------------------------
// Fused dual-A GEMM: y1 = A1@B, y2c = 2*(A2@B) - xg_seg0, sharing the B tile.
// 32 MFMA/wave/iter; single epilogue writes xg seg1 + seg2.
__device__ __forceinline__ void gemm2_body(
    const _Float16* __restrict__ A1, const _Float16* __restrict__ A2,
    const _Float16* __restrict__ Bt, _Float16* xg,
    int bx, int by, int tid,
    _Float16* As1, _Float16* As2, _Float16* Bs) {
  const int wave = tid >> 6, lane = tid & 63;
  const int m0 = by * 128, c0 = bx * 64;
  const int lrow = lane >> 3;
  const int lchunk = lane & 7;
  const int fm = lane & 15, fq = lane >> 4;
  f32x4 acc1[2][4] = {}, acc2[2][4] = {};
  for (int ks = 0; ks < 16; ks++) {
    const int kp = ks * 64;
#pragma unroll
    for (int q = 0; q < 4; q++) {          // A1+A2: 16 groups of 8 rows each
      const int seg = wave * 4 + q;
      const int row = seg * 8 + lrow;
      const int sw = lchunk ^ (row & 7);
      const size_t go = (size_t)(m0 + row) * 1024 + kp + sw * 8;
      gl_lds16(A1 + go, &As1[seg * 8 * 64], lane);
      gl_lds16(A2 + go, &As2[seg * 8 * 64], lane);
    }
#pragma unroll
    for (int q = 0; q < 2; q++) {          // B: 8 groups of 8 rows
      const int seg = wave * 2 + q;
      const int row = seg * 8 + lrow;
      const int sw = lchunk ^ (row & 7);
      gl_lds16(Bt + (size_t)(c0 + row) * 1024 + kp + sw * 8, &Bs[seg * 8 * 64], lane);
    }
    __syncthreads();
#pragma unroll
    for (int kk = 0; kk < 2; kk++) {
      f16x8 a1[2], a2[2], bfr[4];
      const int g = kk * 4 + fq;
#pragma unroll
      for (int mt = 0; mt < 2; mt++) {
        const int row = wave * 32 + mt * 16 + fm;
        const int o = row * 64 + (g ^ (row & 7)) * 8;
        a1[mt] = *(const f16x8*)&As1[o];
        a2[mt] = *(const f16x8*)&As2[o];
      }
#pragma unroll
      for (int nt = 0; nt < 4; nt++) {
        const int row = nt * 16 + fm;
        bfr[nt] = *(const f16x8*)&Bs[row * 64 + (g ^ (row & 7)) * 8];
      }
#pragma unroll
      for (int mt = 0; mt < 2; mt++)
#pragma unroll
        for (int nt = 0; nt < 4; nt++) {
          acc1[mt][nt] = __builtin_amdgcn_mfma_f32_16x16x32_f16(a1[mt], bfr[nt], acc1[mt][nt], 0, 0, 0);
          acc2[mt][nt] = __builtin_amdgcn_mfma_f32_16x16x32_f16(a2[mt], bfr[nt], acc2[mt][nt], 0, 0, 0);
        }
    }
    __syncthreads();
  }
  const int q4 = fq * 4;
#pragma unroll
  for (int nt = 0; nt < 4; nt++) {
    const int col = c0 + nt * 16 + fm;
    if (col >= BC_) continue;
    const u32 bq = div65((u32)col), cq = (u32)col - bq * 65;
#pragma unroll
    for (int mt = 0; mt < 2; mt++) {
      const int row = m0 + wave * 32 + mt * 16 + q4;
      const f32x4 v1 = acc1[mt][nt];
      const f32x4 v2 = acc2[mt][nt];
#pragma unroll
      for (int j = 0; j < 4; j++) {
        size_t base = ((size_t)(row + j) * 64 + bq) * KP_;
        xg[base + 65 + cq] = (_Float16)v1[j];
        xg[base + 130 + cq] = (_Float16)(2.f * v2[j] - (float)xg[base + cq]);
      }
    }
  }
}

// ---------------------------------------------------------------------------
// Prologue 1: wprep gate [0,224), wprep upd [224,448), compute_e all t [448,496).
__global__ __launch_bounds__(256) void k_pre0(
    const float* __restrict__ gate_wp, const float* __restrict__ upd_wp,
    _Float16* __restrict__ wpCg, _Float16* __restrict__ wpCu,
    const float* __restrict__ node_emb, const float* __restrict__ time_emb,
    const float* __restrict__ g_lng, const float* __restrict__ g_lnb,
    const float* __restrict__ u_lng, const float* __restrict__ u_lnb,
    float* __restrict__ eg_all, float* __restrict__ egT_all,
    float* __restrict__ eu_all, float* __restrict__ euT_all) {
  const int bid = blockIdx.x, tid = threadIdx.x;
  if (bid < KP_)     { wprep_body(gate_wp, OG_, wpCg, bid, tid); return; }
  if (bid < 2 * KP_) { wprep_body(upd_wp,  OU_, wpCu, bid - KP_, tid); return; }
  const int idx = bid - 2 * KP_;          // 0..47
  const int t = idx >> 2;
  const int n = (idx & 3) * 256 + tid;
  float v[E_];
  float m = 0.f;
#pragma unroll
  for (int d = 0; d < E_; d++) { v[d] = node_emb[n * E_ + d] + time_emb[t * E_ + d]; m += v[d]; }
  m *= (1.0f / E_);
  float var = 0.f;
#pragma unroll
  for (int d = 0; d < E_; d++) { float x = v[d] - m; var += x * x; }
  var *= (1.0f / E_);
  float rs = rsqrtf(var + EPS_);
#pragma unroll
  for (int d = 0; d < E_; d++) {
    float nv = (v[d] - m) * rs;
    float g = nv * g_lng[d] + g_lnb[d];
    float u = nv * u_lng[d] + u_lnb[d];
    eg_all[(size_t)t * NE_ + n * E_ + d] = g;
    egT_all[(size_t)t * NE_ + d * N_ + n] = g;
    eu_all[(size_t)t * NE_ + n * E_ + d] = u;
    euT_all[(size_t)t * NE_ + d * N_ + n] = u;
  }
}

// ---------------------------------------------------------------------------
// Prologue 2: sup gate t=0 [0,1024), sup upd t=0 [1024,2048),
// build0 (gate X = [x_0 | 0], pads zeroed) [2048,3072).
__global__ __launch_bounds__(256) void k_pro(
    const float* __restrict__ egT0, const float* __restrict__ euT0,
    const float* __restrict__ src,
    _Float16* __restrict__ supG, _Float16* __restrict__ supU0,
    _Float16* __restrict__ Xt, _Float16* __restrict__ xg) {
  __shared__ float red[256];
  const int bid = blockIdx.x, tid = threadIdx.x;
  if (bid < 1024) { sup_body(egT0, supG, bid, tid, red); return; }
  if (bid < 2048) { sup_body(euT0, supU0, bid - 1024, tid, red); return; }
  const int idx = bid - 2048;
  const int b = idx & 63, m0 = (idx >> 6) * 64;
  for (int q = 0; q < 17; q++) {
    int i = tid + q * 256;
    if (i < 64 * 65) {
      int c = i >> 6, m = i & 63;
      float xv = (c == 0) ? src[((size_t)b * T_) * N_ + m0 + m] : 0.f;
      Xt[((size_t)(b * C_ + c)) * 1024 + m0 + m] = (_Float16)xv;
      u32 mm = div65((u32)i), cc = (u32)i - mm * 65;
      float xv2 = (cc == 0) ? src[((size_t)b * T_) * N_ + m0 + mm] : 0.f;
      xg[((size_t)(m0 + mm) * 64 + b) * KP_ + cc] = (_Float16)xv2;
    }
  }
#pragma unroll
  for (int q = 0; q < 8; q++) {
    int i = tid + q * 256;
    int mm = i >> 5, kk = 192 + (i & 31);
    xg[((size_t)(m0 + mm) * 64 + b) * KP_ + kk] = (_Float16)0.f;
  }
}

// Prologue 3: transpose supG0 [0,256), supU0 [256,512).
__global__ __launch_bounds__(256) void k_proT(
    const _Float16* __restrict__ supG0, const _Float16* __restrict__ supU0,
    _Float16* __restrict__ supGT, _Float16* __restrict__ supUT) {
  __shared__ _Float16 lds[64][66];
  const int bid = blockIdx.x;
  if (bid < 256) supT_body(supG0, supGT, bid, threadIdx.x, lds);
  else           supT_body(supU0, supUT, bid - 256, threadIdx.x, lds);
}

// Prologue 4: sup2G0 [0,128), sup2U0 [128,256).
__global__ __launch_bounds__(256) void k_pro2(
    const _Float16* __restrict__ supG0, const _Float16* __restrict__ supGT,
    const _Float16* __restrict__ supU0, const _Float16* __restrict__ supUT,
    _Float16* __restrict__ sup2G0, _Float16* __restrict__ sup2U0) {
  __shared__ __align__(16) _Float16 smem[12288];
  const int bid = blockIdx.x, tid = threadIdx.x;
  if (bid < 128)
    gemm_body(supG0, supGT, sup2G0, bid % 16, bid / 16, tid, smem, smem + 8192);
  else
    gemm_body(supU0, supUT, sup2U0, (bid - 128) % 16, (bid - 128) / 16, tid, smem, smem + 8192);
}

// ---------------------------------------------------------------------------
// Transpose xg seg0 [m][b][0..65) -> Xt [col=(b,c)][m].  Grid (b, m-tile) = 1024.
__global__ __launch_bounds__(256) void k_tr(const _Float16* __restrict__ xg,
                                            _Float16* __restrict__ Xt) {
  __shared__ _Float16 tile[64][66];
  const int b = blockIdx.x & 63, m0 = (blockIdx.x >> 6) * 64;
  const int tid = threadIdx.x;
  {
    const int m = tid >> 2, c4 = tid & 3;
    const _Float16* rp = &xg[((size_t)(m0 + m) * 64 + b) * KP_ + c4 * 16];
    f16x8 v0 = *(const f16x8*)rp;
    f16x8 v1 = *(const f16x8*)(rp + 8);
#pragma unroll
    for (int i = 0; i < 8; i++) {
      tile[m][c4 * 16 + i] = v0[i];
      tile[m][c4 * 16 + 8 + i] = v1[i];
    }
    if (c4 == 0) tile[m][64] = rp[64];
  }
  __syncthreads();
  {
    const int m = tid & 63, cg = tid >> 6;
    for (int cc = cg; cc < 65; cc += 4)
      Xt[((size_t)(b * C_ + cc)) * 1024 + m0 + m] = tile[m][cc];
  }
}

// ---------------------------------------------------------------------------
// kA: fused gate y1+y2 GEMM [0,528) + wgen gate [528,976)
//     + sup(t+1)G [976,2000) + sup(t+1)U [2000,3024)
__global__ __launch_bounds__(256) void k_ga(
    const _Float16* __restrict__ supG_t, const _Float16* __restrict__ sup2G_t,
    const _Float16* __restrict__ Xt, _Float16* xg,
    const float* __restrict__ eg_t, const _Float16* __restrict__ wpCg,
    _Float16* __restrict__ WtG,
    const float* __restrict__ egT_nx, const float* __restrict__ euT_nx,
    _Float16* __restrict__ supG_nx, _Float16* __restrict__ supU_nx) {
  __shared__ __align__(16) _Float16 smem[20480];   // 40 KB
  const int bid = blockIdx.x, tid = threadIdx.x;
  if (bid < 528) {
    gemm2_body(supG_t, sup2G_t, Xt, xg, bid % 66, bid / 66, tid,
               smem, smem + 8192, smem + 16384);
  } else if (bid < 976) {
    const int w = bid - 528;
    wgen_body(eg_t, wpCg, COLG_, WtG, w % 28, w / 28, tid, (float(*)[16])smem);
  } else if (bid < 2000) {
    sup_body(egT_nx, supG_nx, bid - 976, tid, (float*)smem);
  } else {
    sup_body(euT_nx, supU_nx, bid - 2000, tid, (float*)smem);
  }
}

// ---------------------------------------------------------------------------
// kB: gate contract [0,1024) + supGT(t+1) [1024,1280) + supUT(t+1) [1280,1536)
__global__ __launch_bounds__(256) void k_cgT(
    const float* __restrict__ eg, const _Float16* XG,
    const _Float16* __restrict__ Wt, const float* __restrict__ bp,
    const _Float16* __restrict__ h16, const float* __restrict__ src, int t,
    _Float16* __restrict__ r16, _Float16* xgo,
    const _Float16* __restrict__ supG_nx, const _Float16* __restrict__ supU_nx,
    _Float16* __restrict__ supGT, _Float16* __restrict__ supUT) {
  __shared__ __align__(16) char smraw[19456];
  const int bid = blockIdx.x;
  const int tid = threadIdx.x;
  if (bid >= 1024) {
    _Float16 (*lds)[66] = (_Float16(*)[66])smraw;
    if (bid < 1280) supT_body(supG_nx, supGT, bid - 1024, tid, lds);
    else            supT_body(supU_nx, supUT, bid - 1280, tid, lds);
    return;
  }
  float* es = (float*)smraw;
  float* bias_s = (float*)(smraw + 64);
  _Float16 (*zs)[72] = (_Float16(*)[72])(smraw + 576);
  _Float16 (*rs)[72] = (_Float16(*)[72])(smraw + 9792);
  const int n = bid;
  const int wave = tid >> 6, lane = tid & 63;
  const int fm = lane & 15, fq = lane >> 4;
  const int wm = wave >> 1, wn = wave & 1;
  if (tid < 16) es[tid] = eg[n * 16 + tid];
  __syncthreads();
  if (tid < 128) {
    float bv = 0.f;
#pragma unroll
    for (int d = 0; d < 16; d++) bv = fmaf(es[d], bp[d * OG_ + tid], bv);
    bias_s[tid] = bv;
  }
  const _Float16* Ab = XG + (size_t)n * 64 * KP_;
  const _Float16* Bb = Wt + (size_t)n * OG_ * KP_;
  f16x8 af[2][2], bf[2][4];
#pragma unroll
  for (int mt = 0; mt < 2; mt++)
    af[0][mt] = *(const f16x8*)&Ab[(wm * 32 + mt * 16 + fm) * KP_ + fq * 8];
#pragma unroll
  for (int nt = 0; nt < 4; nt++)
    bf[0][nt] = *(const f16x8*)&Bb[(wn * 64 + nt * 16 + fm) * KP_ + fq * 8];
  f32x4 acc[2][4] = {};
#pragma unroll
  for (int kk = 0; kk < 7; kk++) {
    const int cur = kk & 1;
    if (kk < 6) {
      const int ko = (kk + 1) * 32 + fq * 8;
#pragma unroll
      for (int mt = 0; mt < 2; mt++)
        af[cur ^ 1][mt] = *(const f16x8*)&Ab[(wm * 32 + mt * 16 + fm) * KP_ + ko];
#pragma unroll
      for (int nt = 0; nt < 4; nt++)
        bf[cur ^ 1][nt] = *(const f16x8*)&Bb[(wn * 64 + nt * 16 + fm) * KP_ + ko];
    }
#pragma unroll
    for (int mt = 0; mt < 2; mt++)
#pragma unroll
      for (int nt = 0; nt < 4; nt++)
        acc[mt][nt] = __builtin_amdgcn_mfma_f32_16x16x32_f16(af[cur][mt], bf[cur][nt], acc[mt][nt], 0, 0, 0);
  }
  __syncthreads();
#pragma unroll
  for (int nt = 0; nt < 4; nt++) {
    const int o = wn * 64 + nt * 16 + fm;
    const float bias = bias_s[o];
#pragma unroll
    for (int mt = 0; mt < 2; mt++) {
      const f32x4 v = acc[mt][nt];
#pragma unroll
      for (int j = 0; j < 4; j++) {
        const int b = wm * 32 + mt * 16 + fq * 4 + j;
        float s = 1.0f / (1.0f + __expf(-(v[j] + bias)));
        if (wn == 0) zs[b][o] = (_Float16)s;
        else         rs[b][o - H_] = (_Float16)s;
      }
    }
  }
  __syncthreads();
  {
    const int b = tid >> 2, q = tid & 3;
    const _Float16* hp = &h16[((size_t)b * N_ + n) * H_ + q * 16];
    _Float16* xp = &xgo[((size_t)n * 64 + b) * KP_ + 1 + q * 16];
    _Float16* rp = &r16[((size_t)b * N_ + n) * H_ + q * 16];
    f16x8 r0, r1;
#pragma unroll
    for (int i = 0; i < 8; i++) {
      r0[i] = rs[b][q * 16 + i];
      r1[i] = rs[b][q * 16 + 8 + i];
    }
    *(f16x8*)rp = r0;
    *(f16x8*)(rp + 8) = r1;
    f16x8 h0 = *(const f16x8*)hp;
    f16x8 h1 = *(const f16x8*)(hp + 8);
    f16x8 x0, x1;
#pragma unroll
    for (int i = 0; i < 8; i++) {
      x0[i] = (_Float16)((float)zs[b][q * 16 + i] * (float)h0[i]);
      x1[i] = (_Float16)((float)zs[b][q * 16 + 8 + i] * (float)h1[i]);
    }
    *(f16x8*)xp = x0;
    *(f16x8*)(xp + 8) = x1;
    if (tid < 64) {
      float sv = src[((size_t)tid * T_ + t) * N_ + n];
      xgo[((size_t)n * 64 + tid) * KP_] = (_Float16)sv;
    }
  }
}

// ---------------------------------------------------------------------------
// kC: fused upd y1+y2 GEMM [0,528) + wgen upd [528,752)
//     + sup2G(t+1) GEMM [752,880) + sup2U(t+1) GEMM [880,1008)
__global__ __launch_bounds__(256) void k_gu(
    const _Float16* __restrict__ supU_t, const _Float16* __restrict__ sup2U_t,
    const _Float16* __restrict__ Xt, _Float16* xg,
    const float* __restrict__ eu_t, const _Float16* __restrict__ wpCu,
    _Float16* __restrict__ WtU,
    const _Float16* __restrict__ supG_nx, const _Float16* __restrict__ supGT,
    const _Float16* __restrict__ supU_nx, const _Float16* __restrict__ supUT,
    _Float16* __restrict__ sup2G_nx, _Float16* __restrict__ sup2U_nx) {
  __shared__ __align__(16) _Float16 smem[20480];   // 40 KB
  const int bid = blockIdx.x, tid = threadIdx.x;
  if (bid < 528) {
    gemm2_body(supU_t, sup2U_t, Xt, xg, bid % 66, bid / 66, tid,
               smem, smem + 8192, smem + 16384);
  } else if (bid < 752) {
    const int w = bid - 528;
    wgen_body(eu_t, wpCu, COLU_, WtU, w % 14, w / 14, tid, (float(*)[16])smem);
  } else if (bid < 880) {
    const int w = bid - 752;
    gemm_body(supG_nx, supGT, sup2G_nx, w % 16, w / 16, tid, smem, smem + 8192);
  } else {
    const int w = bid - 880;
    gemm_body(supU_nx, supUT, sup2U_nx, w % 16, w / 16, tid, smem, smem + 8192);
  }
}

// ---------------------------------------------------------------------------
// Fused upd contract: MFMA hc; h_new = r*h + (1-r)*hc via fp16 LDS; writes h
// (coalesced) and (t<11) next gate inputs into xg seg0.
__global__ __launch_bounds__(256) void k_cu(
    const float* __restrict__ eu, const _Float16* XG,
    const _Float16* __restrict__ Wt, const float* __restrict__ bp,
    const _Float16* __restrict__ r16, const float* __restrict__ src,
    int t, int donext,
    _Float16* __restrict__ h16, _Float16* xgo) {
  const int n = blockIdx.x;
  const int tid = threadIdx.x;
  const int wave = tid >> 6, lane = tid & 63;
  const int fm = lane & 15, fq = lane >> 4;
  __shared__ float es[16];
  __shared__ float bias_s[64];
  __shared__ _Float16 hs[64][72];
  __shared__ _Float16 rs[64][72];
  if (tid < 16) es[tid] = eu[n * 16 + tid];
  __syncthreads();
  if (tid < 64) {
    float bv = 0.f;
#pragma unroll
    for (int d = 0; d < 16; d++) bv = fmaf(es[d], bp[d * OU_ + tid], bv);
    bias_s[tid] = bv;
  }
  {
    const int b = tid >> 2, q = tid & 3;
    const _Float16* hp = &h16[((size_t)b * N_ + n) * H_ + q * 16];
    const _Float16* rp = &r16[((size_t)b * N_ + n) * H_ + q * 16];
    f16x8 h0 = *(const f16x8*)hp;
    f16x8 h1 = *(const f16x8*)(hp + 8);
    f16x8 r0 = *(const f16x8*)rp;
    f16x8 r1 = *(const f16x8*)(rp + 8);
#pragma unroll
    for (int i = 0; i < 8; i++) {
      hs[b][q * 16 + i] = h0[i];
      hs[b][q * 16 + 8 + i] = h1[i];
      rs[b][q * 16 + i] = r0[i];
      rs[b][q * 16 + 8 + i] = r1[i];
    }
  }
  __syncthreads();
  const _Float16* Ab = XG + (size_t)n * 64 * KP_;
  const _Float16* Bb = Wt + (size_t)n * OU_ * KP_;
  f16x8 af[2], bf[2][4];
  af[0] = *(const f16x8*)&Ab[(wave * 16 + fm) * KP_ + fq * 8];
#pragma unroll
  for (int nt = 0; nt < 4; nt++)
    bf[0][nt] = *(const f16x8*)&Bb[(nt * 16 + fm) * KP_ + fq * 8];
  f32x4 acc[4] = {};
#pragma unroll
  for (int kk = 0; kk < 7; kk++) {
    const int cur = kk & 1;
    if (kk < 6) {
      const int ko = (kk + 1) * 32 + fq * 8;
      af[cur ^ 1] = *(const f16x8*)&Ab[(wave * 16 + fm) * KP_ + ko];
#pragma unroll
      for (int nt = 0; nt < 4; nt++)
        bf[cur ^ 1][nt] = *(const f16x8*)&Bb[(nt * 16 + fm) * KP_ + ko];
    }
#pragma unroll
    for (int nt = 0; nt < 4; nt++)
      acc[nt] = __builtin_amdgcn_mfma_f32_16x16x32_f16(af[cur], bf[cur][nt], acc[nt], 0, 0, 0);
  }
#pragma unroll
  for (int nt = 0; nt < 4; nt++) {
    const int o = nt * 16 + fm;
    const float bias = bias_s[o];
    const f32x4 v = acc[nt];
#pragma unroll
    for (int j = 0; j < 4; j++) {
      const int b = wave * 16 + fq * 4 + j;
      float hc = tanhf(v[j] + bias);
      float rv = (float)rs[b][o];
      float hv = (float)hs[b][o];
      hs[b][o] = (_Float16)(rv * hv + (1.0f - rv) * hc);
    }
  }
  __syncthreads();
  {
    const int b = tid >> 2, q = tid & 3;
    _Float16* hp = &h16[((size_t)b * N_ + n) * H_ + q * 16];
    f16x8 h0, h1;
#pragma unroll
    for (int i = 0; i < 8; i++) {
      h0[i] = hs[b][q * 16 + i];
      h1[i] = hs[b][q * 16 + 8 + i];
    }
    *(f16x8*)hp = h0;
    *(f16x8*)(hp + 8) = h1;
    if (donext) {
      _Float16* xp = &xgo[((size_t)n * 64 + b) * KP_ + 1 + q * 16];
      *(f16x8*)xp = h0;
      *(f16x8*)(xp + 8) = h1;
      if (tid < 64) {
        float sv = src[((size_t)tid * T_ + (t + 1)) * N_ + n];
        xgo[((size_t)n * 64 + tid) * KP_] = (_Float16)sv;
      }
    }
  }
}

// ---------------------------------------------------------------------------
// LN(h) + conv, one thread per (b,n).  h fp16.
__global__ __launch_bounds__(256) void k_final(const _Float16* __restrict__ h16,
                                               const float* __restrict__ out_lng,
                                               const float* __restrict__ out_lnb,
                                               const float* __restrict__ conv_w,
                                               const float* __restrict__ conv_b,
                                               float* __restrict__ out) {
  const int b = blockIdx.x >> 2;
  const int n = (blockIdx.x & 3) * 256 + threadIdx.x;
  __shared__ float cw[12][64];
  __shared__ float cb[12];
  __shared__ float lgs[64], lbs[64];
  for (int idx = threadIdx.x; idx < 12 * 64; idx += 256) cw[idx >> 6][idx & 63] = conv_w[idx];
  if (threadIdx.x < 12) cb[threadIdx.x] = conv_b[threadIdx.x];
  if (threadIdx.x < 64) { lgs[threadIdx.x] = out_lng[threadIdx.x]; lbs[threadIdx.x] = out_lnb[threadIdx.x]; }
  __syncthreads();
  const _Float16* hp = &h16[((size_t)b * N_ + n) * H_];
  float hv[64];
  float mean = 0.f;
#pragma unroll
  for (int i8 = 0; i8 < 8; i8++) {
    f16x8 v = *(const f16x8*)&hp[i8 * 8];
#pragma unroll
    for (int j = 0; j < 8; j++) { hv[i8 * 8 + j] = (float)v[j]; mean += hv[i8 * 8 + j]; }
  }
  mean *= (1.0f / H_);
  float var = 0.f;
#pragma unroll
  for (int i = 0; i < 64; i++) { float d = hv[i] - mean; var += d * d; }
  var *= (1.0f / H_);
  const float rs = rsqrtf(var + EPS_);
  float y[64];
#pragma unroll
  for (int i = 0; i < 64; i++)
    y[i] = (hv[i] - mean) * rs * lgs[i] + lbs[i];
#pragma unroll
  for (int o = 0; o < 12; o++) {
    float acc = cb[o];
#pragma unroll
    for (int i = 0; i < 64; i++) acc = fmaf(y[i], cw[o][i], acc);
    out[((size_t)b * 12 + o) * N_ + n] = acc;
  }
}

// ---------------------------------------------------------------------------
extern "C" void kernel_launch(void* const* d_in, const int* in_sizes, int n_in,
                              void* d_out, int out_size, void* d_ws, size_t ws_size,
                              hipStream_t stream) {
  const float* src      = (const float*)d_in[0];
  const float* node_emb = (const float*)d_in[1];
  const float* time_emb = (const float*)d_in[2];
  const float* gate_wp  = (const float*)d_in[3];
  const float* gate_bp  = (const float*)d_in[4];
  const float* gate_lng = (const float*)d_in[5];
  const float* gate_lnb = (const float*)d_in[6];
  const float* upd_wp   = (const float*)d_in[7];
  const float* upd_bp   = (const float*)d_in[8];
  const float* upd_lng  = (const float*)d_in[9];
  const float* upd_lnb  = (const float*)d_in[10];
  const float* out_lng  = (const float*)d_in[11];
  const float* out_lnb  = (const float*)d_in[12];
  const float* conv_w   = (const float*)d_in[13];
  const float* conv_b   = (const float*)d_in[14];
  float* out = (float*)d_out;

  constexpr size_t SZ_H16 = (size_t)B_ * N_ * H_ / 2;    // h fp16
  constexpr size_t SZ_R   = SZ_H16;                      // r fp16
  constexpr size_t SZ_T   = (size_t)BC_ * 1024 / 2;      // Xt: 2,129,920
  constexpr size_t SZ_XG  = (size_t)N_ * 64 * KP_ / 2;   // 7,340,032
  constexpr size_t SZ_WT  = (size_t)N_ * OG_ * KP_ / 2;  // 14,680,064 (WtU aliases 1st half)
  constexpr size_t SZ_WCG = (size_t)COLG_ * 16 / 2;      // 229,376
  constexpr size_t SZ_WCU = (size_t)COLU_ * 16 / 2;      // 114,688
  constexpr size_t SZ_S   = (size_t)N_ * N_ / 2;         // 524,288 (one fp16 NxN)

  float* ws = (float*)d_ws;
  size_t off = 0;
  float* h16F   = ws + off; off += SZ_H16;
  float* r16F   = ws + off; off += SZ_R;
  float* XtF    = ws + off; off += SZ_T;
  float* xgF    = ws + off; off += SZ_XG;
  float* WtF    = ws + off; off += SZ_WT;
  float* wcgF   = ws + off; off += SZ_WCG;
  float* wcuF   = ws + off; off += SZ_WCU;
  float* supGF  = ws + off; off += 2 * SZ_S;   // double-buffered
  float* supUF  = ws + off; off += 2 * SZ_S;
  float* supGTF = ws + off; off += SZ_S;
  float* supUTF = ws + off; off += SZ_S;
  float* s2GF   = ws + off; off += 2 * SZ_S;
  float* s2UF   = ws + off; off += 2 * SZ_S;
  float* eg_all  = ws + off; off += (size_t)T_ * NE_;
  float* egT_all = ws + off; off += (size_t)T_ * NE_;
  float* eu_all  = ws + off; off += (size_t)T_ * NE_;
  float* euT_all = ws + off; off += (size_t)T_ * NE_;
  if (ws_size < off * sizeof(float)) return;   // ~139 MB

  _Float16* h16   = (_Float16*)h16F;
  _Float16* r16   = (_Float16*)r16F;
  _Float16* Xt    = (_Float16*)XtF;
  _Float16* xg    = (_Float16*)xgF;
  _Float16* WtG   = (_Float16*)WtF;
  _Float16* WtU   = (_Float16*)WtF;
  _Float16* wpCg  = (_Float16*)wcgF;
  _Float16* wpCu  = (_Float16*)wcuF;
  _Float16* supG  = (_Float16*)supGF;
  _Float16* supU  = (_Float16*)supUF;
  _Float16* supGT = (_Float16*)supGTF;
  _Float16* supUT = (_Float16*)supUTF;
  _Float16* s2G   = (_Float16*)s2GF;
  _Float16* s2U   = (_Float16*)s2UF;
  const size_t SB = (size_t)N_ * N_;   // fp16 elements per sup matrix

  hipMemsetAsync(h16, 0, SZ_H16 * sizeof(float), stream);
  k_pre0<<<2 * KP_ + 48, 256, 0, stream>>>(gate_wp, upd_wp, wpCg, wpCu,
                                           node_emb, time_emb,
                                           gate_lng, gate_lnb, upd_lng, upd_lnb,
                                           eg_all, egT_all, eu_all, euT_all);
  k_pro<<<3072, 256, 0, stream>>>(egT_all, euT_all, src, supG, supU, Xt, xg);
  k_proT<<<512, 256, 0, stream>>>(supG, supU, supGT, supUT);
  k_pro2<<<256, 256, 0, stream>>>(supG, supGT, supU, supUT, s2G, s2U);

  for (int t = 0; t < T_; t++) {
    const int cur = t & 1, nxt = (t + 1) & 1;
    _Float16* supG_t  = supG + (size_t)cur * SB;
    _Float16* supG_nx = supG + (size_t)nxt * SB;
    _Float16* supU_t  = supU + (size_t)cur * SB;
    _Float16* supU_nx = supU + (size_t)nxt * SB;
    _Float16* s2G_t   = s2G + (size_t)cur * SB;
    _Float16* s2G_nx  = s2G + (size_t)nxt * SB;
    _Float16* s2U_t   = s2U + (size_t)cur * SB;
    _Float16* s2U_nx  = s2U + (size_t)nxt * SB;
    const float* eg_t = eg_all + (size_t)t * NE_;
    const float* eu_t = eu_all + (size_t)t * NE_;
    const int more = (t < T_ - 1) ? 1 : 0;
    const int tn = more ? t + 1 : t;

    k_ga<<<more ? 3024 : 976, 256, 0, stream>>>(
        supG_t, s2G_t, Xt, xg, eg_t, wpCg, WtG,
        egT_all + (size_t)tn * NE_, euT_all + (size_t)tn * NE_, supG_nx, supU_nx);
    k_cgT<<<more ? 1536 : 1024, 256, 0, stream>>>(
        eg_t, xg, WtG, gate_bp, h16, src, t, r16, xg,
        supG_nx, supU_nx, supGT, supUT);
    k_tr<<<1024, 256, 0, stream>>>(xg, Xt);        // upd X -> Xt
    k_gu<<<more ? 1008 : 752, 256, 0, stream>>>(
        supU_t, s2U_t, Xt, xg, eu_t, wpCu, WtU,
        supG_nx, supGT, supU_nx, supUT, s2G_nx, s2U_nx);
    k_cu<<<N_, 256, 0, stream>>>(eu_t, xg, WtU, upd_bp, r16, src, t, more, h16, xg);
    if (more) k_tr<<<1024, 256, 0, stream>>>(xg, Xt);   // next gate X -> Xt
  }
  k_final<<<B_ * N_ / 256, 256, 0, stream>>>(h16, out_lng, out_lnb, conv_w, conv_b, out);
}

// Round 13
// 1860.139 us; speedup vs baseline: 1.1281x; 1.1281x over previous
//
#include <hip/hip_runtime.h>
#include <math.h>

namespace {
constexpr int B_ = 64, T_ = 12, N_ = 1024, H_ = 64, E_ = 16;
constexpr int C_  = 65;          // DIN + H
constexpr int BC_ = B_ * C_;     // 4160
constexpr int NPAD_ = 4224;      // Xt row allocation (64-padded)
constexpr int OG_ = 128;         // gate output = 2H
constexpr int OU_ = 64;          // update output = H
constexpr float EPS_ = 1e-12f;
constexpr int KP_ = 224;         // packed contract K: 3*65=195 + pad to 7*32
constexpr int KS_ = 232;         // LDS-staged row stride (bank-friendly, 464B)
constexpr int COLG_ = OG_ * KP_; // 28672
constexpr int COLU_ = OU_ * KP_; // 14336
constexpr int NE_ = N_ * E_;     // 16384
}

typedef unsigned short u16;
typedef unsigned int u32;
using f16x8 = __attribute__((ext_vector_type(8))) _Float16;
using f16x4 = __attribute__((ext_vector_type(4))) _Float16;
using f32x4 = __attribute__((ext_vector_type(4))) float;

__device__ __forceinline__ u32 div65(u32 x) { return (x * 16135u) >> 20; }  // exact for x<5196
__device__ __forceinline__ u32 div29(u32 x) { return (x * 565u) >> 14; }    // exact for x<1857

// async global->LDS 16B/lane; LDS dest is wave-uniform base + lane*16.
__device__ __forceinline__ void gl_lds16(const void* g, void* l, int lane) {
#if __has_builtin(__builtin_amdgcn_global_load_lds)
  __builtin_amdgcn_global_load_lds((const __attribute__((address_space(1))) u32*)g,
                                   (__attribute__((address_space(3))) u32*)l, 16, 0, 0);
#else
  *(uint4*)((char*)l + lane * 16) = *(const uint4*)g;
#endif
}

// ---------------------------------------------------------------------------
// device bodies shared by fused kernels
// ---------------------------------------------------------------------------
__device__ __forceinline__ void wprep_body(const float* __restrict__ wp, int NO,
                                           _Float16* __restrict__ wpC, int k, int tid) {
  if (tid >= NO) return;
  f16x8 lo = {}, hi = {};
  if (k < 195) {
    const u32 seg = div65((u32)k);
    const u32 ii = k - seg * 65;
#pragma unroll
    for (int d = 0; d < 8; d++)
      lo[d] = (_Float16)wp[(((size_t)d * 3 + seg) * 65 + ii) * NO + tid];
#pragma unroll
    for (int d = 0; d < 8; d++)
      hi[d] = (_Float16)wp[(((size_t)(d + 8) * 3 + seg) * 65 + ii) * NO + tid];
  }
  _Float16* dst = &wpC[((size_t)tid * KP_ + k) * 16];
  *(f16x8*)dst = lo;
  *(f16x8*)(dst + 8) = hi;
}

__device__ __forceinline__ void sup_body(const float* __restrict__ eT,
                                         _Float16* __restrict__ s16,
                                         int n, int tid, float* red) {
  float en[E_];
#pragma unroll
  for (int d = 0; d < E_; d++) en[d] = eT[d * N_ + n];
  float lg[4];
  float mx = -3.4e38f;
#pragma unroll
  for (int j = 0; j < 4; j++) {
    int m = tid + 256 * j;
    float s = 0.f;
#pragma unroll
    for (int d = 0; d < E_; d++) s = fmaf(en[d], eT[d * N_ + m], s);
    lg[j] = s;
    mx = fmaxf(mx, s);
  }
  red[tid] = mx; __syncthreads();
  for (int off = 128; off > 0; off >>= 1) {
    if (tid < off) red[tid] = fmaxf(red[tid], red[tid + off]);
    __syncthreads();
  }
  mx = red[0]; __syncthreads();
  float sum = 0.f;
#pragma unroll
  for (int j = 0; j < 4; j++) { lg[j] = __expf(lg[j] - mx); sum += lg[j]; }
  red[tid] = sum; __syncthreads();
  for (int off = 128; off > 0; off >>= 1) {
    if (tid < off) red[tid] += red[tid + off];
    __syncthreads();
  }
  float inv = 1.0f / red[0];
#pragma unroll
  for (int j = 0; j < 4; j++)
    s16[(size_t)n * N_ + tid + 256 * j] = (_Float16)(lg[j] * inv);
}

__device__ __forceinline__ void wgen_body(const float* __restrict__ e,
                                          const _Float16* __restrict__ wpC, int COLS,
                                          _Float16* __restrict__ Wt,
                                          int xb, int yb, int tid, float (*es)[16]) {
  const int col0 = xb * 1024 + tid * 4;
  const int n0 = yb * 64;
#pragma unroll
  for (int q = 0; q < 4; q++) {
    int idx = tid + q * 256;
    es[idx >> 4][idx & 15] = e[(size_t)n0 * 16 + idx];
  }
  __syncthreads();
  float wc[4][16];
#pragma unroll
  for (int cc = 0; cc < 4; cc++) {
    f16x8 a = *(const f16x8*)&wpC[(size_t)(col0 + cc) * 16];
    f16x8 b = *(const f16x8*)&wpC[(size_t)(col0 + cc) * 16 + 8];
#pragma unroll
    for (int d = 0; d < 8; d++) { wc[cc][d] = (float)a[d]; wc[cc][8 + d] = (float)b[d]; }
  }
  for (int nn = 0; nn < 64; nn++) {
    float acc[4] = {};
#pragma unroll
    for (int d = 0; d < 16; d++) {
      float ev = es[nn][d];
#pragma unroll
      for (int cc = 0; cc < 4; cc++) acc[cc] = fmaf(ev, wc[cc][d], acc[cc]);
    }
    f16x4 pv;
#pragma unroll
    for (int cc = 0; cc < 4; cc++) pv[cc] = (_Float16)acc[cc];
    *(f16x4*)&Wt[(size_t)(n0 + nn) * COLS + col0] = pv;
  }
}

// 64x64 fp16 transpose tile: ST[m][n] = S[n][m].
__device__ __forceinline__ void supT_body(const _Float16* __restrict__ S,
                                          _Float16* __restrict__ ST,
                                          int tile, int tid, _Float16 (*lds)[66]) {
  const int n0 = (tile >> 4) * 64;
  const int m0 = (tile & 15) * 64;
  {
    const int r = tid >> 2, c0 = (tid & 3) * 16;
    const _Float16* sp = &S[(size_t)(n0 + r) * 1024 + m0 + c0];
    f16x8 a = *(const f16x8*)sp;
    f16x8 b = *(const f16x8*)(sp + 8);
#pragma unroll
    for (int i = 0; i < 8; i++) { lds[r][c0 + i] = a[i]; lds[r][c0 + 8 + i] = b[i]; }
  }
  __syncthreads();
  {
    const int c = tid >> 2, r0 = (tid & 3) * 16;
    f16x8 a, b;
#pragma unroll
    for (int i = 0; i < 8; i++) { a[i] = lds[r0 + i][c]; b[i] = lds[r0 + 8 + i][c]; }
    _Float16* dp = &ST[(size_t)(m0 + c) * 1024 + n0 + r0];
    *(f16x8*)dp = a;
    *(f16x8*)(dp + 8) = b;
  }
}

// ---------------------------------------------------------------------------
// Single-A GEMM body (sup2 = sup @ supT), rowout [row*1024+col].
__device__ __forceinline__ void gemm_body(
    const _Float16* __restrict__ A, const _Float16* __restrict__ Bt,
    _Float16* __restrict__ rowout,
    int bx, int by, int tid, _Float16* As, _Float16* Bs) {
  const int wave = tid >> 6, lane = tid & 63;
  const int m0 = by * 128, c0 = bx * 64;
  const int lrow = lane >> 3;
  const int lchunk = lane & 7;
  const int fm = lane & 15, fq = lane >> 4;
  f32x4 acc[2][4] = {};
  for (int ks = 0; ks < 16; ks++) {
    const int kp = ks * 64;
#pragma unroll
    for (int q = 0; q < 4; q++) {
      const int seg = wave * 4 + q;
      const int row = seg * 8 + lrow;
      const int sw = lchunk ^ (row & 7);
      gl_lds16(A + (size_t)(m0 + row) * 1024 + kp + sw * 8, &As[seg * 8 * 64], lane);
    }
#pragma unroll
    for (int q = 0; q < 2; q++) {
      const int seg = wave * 2 + q;
      const int row = seg * 8 + lrow;
      const int sw = lchunk ^ (row & 7);
      gl_lds16(Bt + (size_t)(c0 + row) * 1024 + kp + sw * 8, &Bs[seg * 8 * 64], lane);
    }
    __syncthreads();
#pragma unroll
    for (int kk = 0; kk < 2; kk++) {
      f16x8 af[2], bfr[4];
      const int g = kk * 4 + fq;
#pragma unroll
      for (int mt = 0; mt < 2; mt++) {
        const int row = wave * 32 + mt * 16 + fm;
        af[mt] = *(const f16x8*)&As[row * 64 + (g ^ (row & 7)) * 8];
      }
#pragma unroll
      for (int nt = 0; nt < 4; nt++) {
        const int row = nt * 16 + fm;
        bfr[nt] = *(const f16x8*)&Bs[row * 64 + (g ^ (row & 7)) * 8];
      }
#pragma unroll
      for (int mt = 0; mt < 2; mt++)
#pragma unroll
        for (int nt = 0; nt < 4; nt++)
          acc[mt][nt] = __builtin_amdgcn_mfma_f32_16x16x32_f16(af[mt], bfr[nt], acc[mt][nt], 0, 0, 0);
    }
    __syncthreads();
  }
  const int q4 = fq * 4;
#pragma unroll
  for (int nt = 0; nt < 4; nt++) {
    const int col = c0 + nt * 16 + fm;
#pragma unroll
    for (int mt = 0; mt < 2; mt++) {
      const int row = m0 + wave * 32 + mt * 16 + q4;
      const f32x4 v = acc[mt][nt];
#pragma unroll
      for (int j = 0; j < 4; j++)
        rowout[(size_t)(row + j) * 1024 + col] = (_Float16)v[j];
    }
  }
}

// ---------------------------------------------------------------------------
// Fused dual-A GEMM: y1row = A1@B, y2row = A2@B, sharing the B tile.
// COALESCED row-major epilogue (wave covers 128B contiguous per row).
__device__ __forceinline__ void gemm2_body(
    const _Float16* __restrict__ A1, const _Float16* __restrict__ A2,
    const _Float16* __restrict__ Bt,
    _Float16* __restrict__ y1row, _Float16* __restrict__ y2row,
    int bx, int by, int tid,
    _Float16* As1, _Float16* As2, _Float16* Bs) {
  const int wave = tid >> 6, lane = tid & 63;
  const int m0 = by * 128, c0 = bx * 64;
  const int lrow = lane >> 3;
  const int lchunk = lane & 7;
  const int fm = lane & 15, fq = lane >> 4;
  f32x4 acc1[2][4] = {}, acc2[2][4] = {};
  for (int ks = 0; ks < 16; ks++) {
    const int kp = ks * 64;
#pragma unroll
    for (int q = 0; q < 4; q++) {
      const int seg = wave * 4 + q;
      const int row = seg * 8 + lrow;
      const int sw = lchunk ^ (row & 7);
      const size_t go = (size_t)(m0 + row) * 1024 + kp + sw * 8;
      gl_lds16(A1 + go, &As1[seg * 8 * 64], lane);
      gl_lds16(A2 + go, &As2[seg * 8 * 64], lane);
    }
#pragma unroll
    for (int q = 0; q < 2; q++) {
      const int seg = wave * 2 + q;
      const int row = seg * 8 + lrow;
      const int sw = lchunk ^ (row & 7);
      gl_lds16(Bt + (size_t)(c0 + row) * 1024 + kp + sw * 8, &Bs[seg * 8 * 64], lane);
    }
    __syncthreads();
#pragma unroll
    for (int kk = 0; kk < 2; kk++) {
      f16x8 a1[2], a2[2], bfr[4];
      const int g = kk * 4 + fq;
#pragma unroll
      for (int mt = 0; mt < 2; mt++) {
        const int row = wave * 32 + mt * 16 + fm;
        const int o = row * 64 + (g ^ (row & 7)) * 8;
        a1[mt] = *(const f16x8*)&As1[o];
        a2[mt] = *(const f16x8*)&As2[o];
      }
#pragma unroll
      for (int nt = 0; nt < 4; nt++) {
        const int row = nt * 16 + fm;
        bfr[nt] = *(const f16x8*)&Bs[row * 64 + (g ^ (row & 7)) * 8];
      }
#pragma unroll
      for (int mt = 0; mt < 2; mt++)
#pragma unroll
        for (int nt = 0; nt < 4; nt++) {
          acc1[mt][nt] = __builtin_amdgcn_mfma_f32_16x16x32_f16(a1[mt], bfr[nt], acc1[mt][nt], 0, 0, 0);
          acc2[mt][nt] = __builtin_amdgcn_mfma_f32_16x16x32_f16(a2[mt], bfr[nt], acc2[mt][nt], 0, 0, 0);
        }
    }
    __syncthreads();
  }
  const int q4 = fq * 4;
#pragma unroll
  for (int nt = 0; nt < 4; nt++) {
    const int col = c0 + nt * 16 + fm;
    if (col >= BC_) continue;
#pragma unroll
    for (int mt = 0; mt < 2; mt++) {
      const int row = m0 + wave * 32 + mt * 16 + q4;
      const f32x4 v1 = acc1[mt][nt];
      const f32x4 v2 = acc2[mt][nt];
#pragma unroll
      for (int j = 0; j < 4; j++) {
        y1row[(size_t)(row + j) * BC_ + col] = (_Float16)v1[j];
        y2row[(size_t)(row + j) * BC_ + col] = (_Float16)v2[j];
      }
    }
  }
}

// ---------------------------------------------------------------------------
// Stage packed contract A-operand into LDS: XGs[64 b][KS_] from row-major bufs.
// seg0 = X0 (x|h or x|u); seg1 = y1; seg2 = 2*y2 - X0; pad 195..223 zeroed.
__device__ __forceinline__ void stage_xg(
    const _Float16* __restrict__ x0p, const _Float16* __restrict__ y1p,
    const _Float16* __restrict__ y2p, int tid, _Float16* __restrict__ XGs) {
  for (int idx = tid; idx < BC_; idx += 256) {
    const u32 b = div65((u32)idx), k = (u32)idx - b * 65;
    XGs[b * KS_ + k] = x0p[idx];
  }
  for (int idx = tid; idx < BC_; idx += 256) {
    const u32 b = div65((u32)idx), k = (u32)idx - b * 65;
    XGs[b * KS_ + 65 + k] = y1p[idx];
  }
  for (int idx = tid; idx < BC_; idx += 256) {
    const u32 b = div65((u32)idx), k = (u32)idx - b * 65;
    XGs[b * KS_ + 130 + k] = (_Float16)(2.f * (float)y2p[idx] - (float)x0p[idx]);
  }
  for (int idx = tid; idx < 64 * 29; idx += 256) {
    const u32 b = div29((u32)idx), k = (u32)idx - b * 29;
    XGs[b * KS_ + 195 + k] = (_Float16)0.f;
  }
}

// ---------------------------------------------------------------------------
// Prologue 1: wprep gate [0,224), wprep upd [224,448), compute_e all t [448,496).
__global__ __launch_bounds__(256) void k_pre0(
    const float* __restrict__ gate_wp, const float* __restrict__ upd_wp,
    _Float16* __restrict__ wpCg, _Float16* __restrict__ wpCu,
    const float* __restrict__ node_emb, const float* __restrict__ time_emb,
    const float* __restrict__ g_lng, const float* __restrict__ g_lnb,
    const float* __restrict__ u_lng, const float* __restrict__ u_lnb,
    float* __restrict__ eg_all, float* __restrict__ egT_all,
    float* __restrict__ eu_all, float* __restrict__ euT_all) {
  const int bid = blockIdx.x, tid = threadIdx.x;
  if (bid < KP_)     { wprep_body(gate_wp, OG_, wpCg, bid, tid); return; }
  if (bid < 2 * KP_) { wprep_body(upd_wp,  OU_, wpCu, bid - KP_, tid); return; }
  const int idx = bid - 2 * KP_;
  const int t = idx >> 2;
  const int n = (idx & 3) * 256 + tid;
  float v[E_];
  float m = 0.f;
#pragma unroll
  for (int d = 0; d < E_; d++) { v[d] = node_emb[n * E_ + d] + time_emb[t * E_ + d]; m += v[d]; }
  m *= (1.0f / E_);
  float var = 0.f;
#pragma unroll
  for (int d = 0; d < E_; d++) { float x = v[d] - m; var += x * x; }
  var *= (1.0f / E_);
  float rs = rsqrtf(var + EPS_);
#pragma unroll
  for (int d = 0; d < E_; d++) {
    float nv = (v[d] - m) * rs;
    float g = nv * g_lng[d] + g_lnb[d];
    float u = nv * u_lng[d] + u_lnb[d];
    eg_all[(size_t)t * NE_ + n * E_ + d] = g;
    egT_all[(size_t)t * NE_ + d * N_ + n] = g;
    eu_all[(size_t)t * NE_ + n * E_ + d] = u;
    euT_all[(size_t)t * NE_ + d * N_ + n] = u;
  }
}

// ---------------------------------------------------------------------------
// Prologue 2: sup gate t=0 [0,1024), sup upd t=0 [1024,2048),
// build0 [2048,3072): Xt = [x_0|0] transposed, X0row = [x_0|0] row-major.
__global__ __launch_bounds__(256) void k_pro(
    const float* __restrict__ egT0, const float* __restrict__ euT0,
    const float* __restrict__ src,
    _Float16* __restrict__ supG, _Float16* __restrict__ supU0,
    _Float16* __restrict__ Xt, _Float16* __restrict__ X0row) {
  __shared__ float red[256];
  const int bid = blockIdx.x, tid = threadIdx.x;
  if (bid < 1024) { sup_body(egT0, supG, bid, tid, red); return; }
  if (bid < 2048) { sup_body(euT0, supU0, bid - 1024, tid, red); return; }
  const int idx = bid - 2048;
  const int b = idx & 63, m0 = (idx >> 6) * 64;
  for (int q = 0; q < 17; q++) {
    int i = tid + q * 256;
    if (i < 64 * 65) {
      int c = i >> 6, m = i & 63;
      float xv = (c == 0) ? src[((size_t)b * T_) * N_ + m0 + m] : 0.f;
      Xt[((size_t)(b * C_ + c)) * 1024 + m0 + m] = (_Float16)xv;
      u32 mm = div65((u32)i), cc = (u32)i - mm * 65;
      float xv2 = (cc == 0) ? src[((size_t)b * T_) * N_ + m0 + mm] : 0.f;
      X0row[((size_t)(m0 + mm)) * BC_ + b * 65 + cc] = (_Float16)xv2;
    }
  }
}

// Prologue 3: transpose supG0 [0,256), supU0 [256,512).
__global__ __launch_bounds__(256) void k_proT(
    const _Float16* __restrict__ supG0, const _Float16* __restrict__ supU0,
    _Float16* __restrict__ supGT, _Float16* __restrict__ supUT) {
  __shared__ _Float16 lds[64][66];
  const int bid = blockIdx.x;
  if (bid < 256) supT_body(supG0, supGT, bid, threadIdx.x, lds);
  else           supT_body(supU0, supUT, bid - 256, threadIdx.x, lds);
}

// Prologue 4: sup2G0 [0,128), sup2U0 [128,256).
__global__ __launch_bounds__(256) void k_pro2(
    const _Float16* __restrict__ supG0, const _Float16* __restrict__ supGT,
    const _Float16* __restrict__ supU0, const _Float16* __restrict__ supUT,
    _Float16* __restrict__ sup2G0, _Float16* __restrict__ sup2U0) {
  __shared__ __align__(16) _Float16 smem[12288];
  const int bid = blockIdx.x, tid = threadIdx.x;
  if (bid < 128)
    gemm_body(supG0, supGT, sup2G0, bid % 16, bid / 16, tid, smem, smem + 8192);
  else
    gemm_body(supU0, supUT, sup2U0, (bid - 128) % 16, (bid - 128) / 16, tid, smem, smem + 8192);
}

// ---------------------------------------------------------------------------
// Transpose X0row [m][4160 col] -> Xt [col][m].  Grid 65 x 16 = 1040.
__global__ __launch_bounds__(256) void k_tr(const _Float16* __restrict__ X0,
                                            _Float16* __restrict__ Xt) {
  __shared__ _Float16 tile[64][66];
  const int c0 = (blockIdx.x % 65) * 64;
  const int m0 = (blockIdx.x / 65) * 64;
  const int tid = threadIdx.x;
#pragma unroll
  for (int q = 0; q < 16; q++) {
    int idx = tid + q * 256;
    int m = idx >> 6, c = idx & 63;
    tile[m][c] = X0[(size_t)(m0 + m) * BC_ + c0 + c];
  }
  __syncthreads();
  {
    const int c = tid >> 2, mq = (tid & 3) * 16;
    f16x8 a, b;
#pragma unroll
    for (int i = 0; i < 8; i++) { a[i] = tile[mq + i][c]; b[i] = tile[mq + 8 + i][c]; }
    _Float16* dp = &Xt[(size_t)(c0 + c) * 1024 + m0 + mq];
    *(f16x8*)dp = a;
    *(f16x8*)(dp + 8) = b;
  }
}

// ---------------------------------------------------------------------------
// kA: fused gate y1+y2 GEMM [0,528) + wgen gate [528,976)
//     + sup(t+1)G [976,2000) + sup(t+1)U [2000,3024)
__global__ __launch_bounds__(256) void k_ga(
    const _Float16* __restrict__ supG_t, const _Float16* __restrict__ sup2G_t,
    const _Float16* __restrict__ Xt,
    _Float16* __restrict__ y1row, _Float16* __restrict__ y2row,
    const float* __restrict__ eg_t, const _Float16* __restrict__ wpCg,
    _Float16* __restrict__ WtG,
    const float* __restrict__ egT_nx, const float* __restrict__ euT_nx,
    _Float16* __restrict__ supG_nx, _Float16* __restrict__ supU_nx) {
  __shared__ __align__(16) _Float16 smem[20480];   // 40 KB
  const int bid = blockIdx.x, tid = threadIdx.x;
  if (bid < 528) {
    gemm2_body(supG_t, sup2G_t, Xt, y1row, y2row, bid % 66, bid / 66, tid,
               smem, smem + 8192, smem + 16384);
  } else if (bid < 976) {
    const int w = bid - 528;
    wgen_body(eg_t, wpCg, COLG_, WtG, w % 28, w / 28, tid, (float(*)[16])smem);
  } else if (bid < 2000) {
    sup_body(egT_nx, supG_nx, bid - 976, tid, (float*)smem);
  } else {
    sup_body(euT_nx, supU_nx, bid - 2000, tid, (float*)smem);
  }
}

// ---------------------------------------------------------------------------
// kB: gate contract [0,1024) + supGT(t+1) [1024,1280) + supUT(t+1) [1280,1536)
// Contract: LDS-staged A from X0/y1/y2 row-major; zs/rs alias XGs post-MFMA.
__global__ __launch_bounds__(256) void k_cgT(
    const float* __restrict__ eg,
    const _Float16* __restrict__ X0, const _Float16* __restrict__ y1r,
    const _Float16* __restrict__ y2r,
    const _Float16* __restrict__ Wt, const float* __restrict__ bp,
    const _Float16* __restrict__ h16, const float* __restrict__ src, int t,
    _Float16* __restrict__ r16, _Float16* X0out,
    const _Float16* __restrict__ supG_nx, const _Float16* __restrict__ supU_nx,
    _Float16* __restrict__ supGT, _Float16* __restrict__ supUT) {
  __shared__ __align__(16) char smraw[30272];
  const int bid = blockIdx.x;
  const int tid = threadIdx.x;
  if (bid >= 1024) {
    _Float16 (*lds)[66] = (_Float16(*)[66])smraw;
    if (bid < 1280) supT_body(supG_nx, supGT, bid - 1024, tid, lds);
    else            supT_body(supU_nx, supUT, bid - 1280, tid, lds);
    return;
  }
  float* es = (float*)smraw;                               // [0,64)
  float* bias_s = (float*)(smraw + 64);                    // [64,576)
  _Float16* XGs = (_Float16*)(smraw + 576);                // [576,30272)
  _Float16 (*zs)[72] = (_Float16(*)[72])(smraw + 576);     // alias (post-MFMA)
  _Float16 (*rs)[72] = (_Float16(*)[72])(smraw + 9792);
  const int n = bid;
  const int wave = tid >> 6, lane = tid & 63;
  const int fm = lane & 15, fq = lane >> 4;
  const int wm = wave >> 1, wn = wave & 1;
  if (tid < 16) es[tid] = eg[n * 16 + tid];
  stage_xg(X0 + (size_t)n * BC_, y1r + (size_t)n * BC_, y2r + (size_t)n * BC_, tid, XGs);
  __syncthreads();
  if (tid < 128) {
    float bv = 0.f;
#pragma unroll
    for (int d = 0; d < 16; d++) bv = fmaf(es[d], bp[d * OG_ + tid], bv);
    bias_s[tid] = bv;
  }
  const _Float16* Bb = Wt + (size_t)n * OG_ * KP_;
  f32x4 acc[2][4] = {};
#pragma unroll
  for (int kk = 0; kk < 7; kk++) {
    const int ko = kk * 32 + fq * 8;
    f16x8 af[2], bf[4];
#pragma unroll
    for (int mt = 0; mt < 2; mt++)
      af[mt] = *(const f16x8*)&XGs[(wm * 32 + mt * 16 + fm) * KS_ + ko];
#pragma unroll
    for (int nt = 0; nt < 4; nt++)
      bf[nt] = *(const f16x8*)&Bb[(wn * 64 + nt * 16 + fm) * KP_ + ko];
#pragma unroll
    for (int mt = 0; mt < 2; mt++)
#pragma unroll
      for (int nt = 0; nt < 4; nt++)
        acc[mt][nt] = __builtin_amdgcn_mfma_f32_16x16x32_f16(af[mt], bf[nt], acc[mt][nt], 0, 0, 0);
  }
  __syncthreads();   // XGs dead; zs/rs alias becomes live
#pragma unroll
  for (int nt = 0; nt < 4; nt++) {
    const int o = wn * 64 + nt * 16 + fm;
    const float bias = bias_s[o];
#pragma unroll
    for (int mt = 0; mt < 2; mt++) {
      const f32x4 v = acc[mt][nt];
#pragma unroll
      for (int j = 0; j < 4; j++) {
        const int b = wm * 32 + mt * 16 + fq * 4 + j;
        float s = 1.0f / (1.0f + __expf(-(v[j] + bias)));
        if (wn == 0) zs[b][o] = (_Float16)s;
        else         rs[b][o - H_] = (_Float16)s;
      }
    }
  }
  __syncthreads();
  {
    const int b = tid >> 2, q = tid & 3;
    const _Float16* hp = &h16[((size_t)b * N_ + n) * H_ + q * 16];
    _Float16* xp = &X0out[(size_t)n * BC_ + b * 65 + 1 + q * 16];
    _Float16* rp = &r16[((size_t)b * N_ + n) * H_ + q * 16];
    f16x8 r0, r1;
#pragma unroll
    for (int i = 0; i < 8; i++) {
      r0[i] = rs[b][q * 16 + i];
      r1[i] = rs[b][q * 16 + 8 + i];
    }
    *(f16x8*)rp = r0;
    *(f16x8*)(rp + 8) = r1;
    f16x8 h0 = *(const f16x8*)hp;
    f16x8 h1 = *(const f16x8*)(hp + 8);
    f16x8 x0, x1;
#pragma unroll
    for (int i = 0; i < 8; i++) {
      x0[i] = (_Float16)((float)zs[b][q * 16 + i] * (float)h0[i]);
      x1[i] = (_Float16)((float)zs[b][q * 16 + 8 + i] * (float)h1[i]);
    }
    *(f16x8*)xp = x0;
    *(f16x8*)(xp + 8) = x1;
    if (tid < 64) {
      float sv = src[((size_t)tid * T_ + t) * N_ + n];
      X0out[(size_t)n * BC_ + tid * 65] = (_Float16)sv;
    }
  }
}

// ---------------------------------------------------------------------------
// kC: fused upd y1+y2 GEMM [0,528) + wgen upd [528,752)
//     + sup2G(t+1) GEMM [752,880) + sup2U(t+1) GEMM [880,1008)
__global__ __launch_bounds__(256) void k_gu(
    const _Float16* __restrict__ supU_t, const _Float16* __restrict__ sup2U_t,
    const _Float16* __restrict__ Xt,
    _Float16* __restrict__ y1row, _Float16* __restrict__ y2row,
    const float* __restrict__ eu_t, const _Float16* __restrict__ wpCu,
    _Float16* __restrict__ WtU,
    const _Float16* __restrict__ supG_nx, const _Float16* __restrict__ supGT,
    const _Float16* __restrict__ supU_nx, const _Float16* __restrict__ supUT,
    _Float16* __restrict__ sup2G_nx, _Float16* __restrict__ sup2U_nx) {
  __shared__ __align__(16) _Float16 smem[20480];   // 40 KB
  const int bid = blockIdx.x, tid = threadIdx.x;
  if (bid < 528) {
    gemm2_body(supU_t, sup2U_t, Xt, y1row, y2row, bid % 66, bid / 66, tid,
               smem, smem + 8192, smem + 16384);
  } else if (bid < 752) {
    const int w = bid - 528;
    wgen_body(eu_t, wpCu, COLU_, WtU, w % 14, w / 14, tid, (float(*)[16])smem);
  } else if (bid < 880) {
    const int w = bid - 752;
    gemm_body(supG_nx, supGT, sup2G_nx, w % 16, w / 16, tid, smem, smem + 8192);
  } else {
    const int w = bid - 880;
    gemm_body(supU_nx, supUT, sup2U_nx, w % 16, w / 16, tid, smem, smem + 8192);
  }
}

// ---------------------------------------------------------------------------
// Fused upd contract: LDS-staged A; MFMA hc; h_new = r*h + (1-r)*hc via fp16
// LDS (aliased over XGs post-MFMA); writes h and (t<11) next gate X0row.
__global__ __launch_bounds__(256) void k_cu(
    const float* __restrict__ eu,
    const _Float16* __restrict__ X0, const _Float16* __restrict__ y1r,
    const _Float16* __restrict__ y2r,
    const _Float16* __restrict__ Wt, const float* __restrict__ bp,
    const _Float16* __restrict__ r16, const float* __restrict__ src,
    int t, int donext,
    _Float16* __restrict__ h16, _Float16* X0out) {
  __shared__ __align__(16) char smraw[30016];
  float* es = (float*)smraw;                               // [0,64)
  float* bias_s = (float*)(smraw + 64);                    // [64,320)
  _Float16* XGs = (_Float16*)(smraw + 320);                // [320,30016)
  _Float16 (*hs)[72] = (_Float16(*)[72])(smraw + 320);     // alias (post-MFMA)
  _Float16 (*rs)[72] = (_Float16(*)[72])(smraw + 9536);
  const int n = blockIdx.x;
  const int tid = threadIdx.x;
  const int wave = tid >> 6, lane = tid & 63;
  const int fm = lane & 15, fq = lane >> 4;
  if (tid < 16) es[tid] = eu[n * 16 + tid];
  stage_xg(X0 + (size_t)n * BC_, y1r + (size_t)n * BC_, y2r + (size_t)n * BC_, tid, XGs);
  __syncthreads();
  if (tid < 64) {
    float bv = 0.f;
#pragma unroll
    for (int d = 0; d < 16; d++) bv = fmaf(es[d], bp[d * OU_ + tid], bv);
    bias_s[tid] = bv;
  }
  const _Float16* Bb = Wt + (size_t)n * OU_ * KP_;
  f32x4 acc[4] = {};
#pragma unroll
  for (int kk = 0; kk < 7; kk++) {
    const int ko = kk * 32 + fq * 8;
    f16x8 af = *(const f16x8*)&XGs[(wave * 16 + fm) * KS_ + ko];
    f16x8 bf[4];
#pragma unroll
    for (int nt = 0; nt < 4; nt++)
      bf[nt] = *(const f16x8*)&Bb[(nt * 16 + fm) * KP_ + ko];
#pragma unroll
    for (int nt = 0; nt < 4; nt++)
      acc[nt] = __builtin_amdgcn_mfma_f32_16x16x32_f16(af, bf[nt], acc[nt], 0, 0, 0);
  }
  __syncthreads();   // XGs dead; hs/rs alias becomes live
  {
    const int b = tid >> 2, q = tid & 3;
    const _Float16* hp = &h16[((size_t)b * N_ + n) * H_ + q * 16];
    const _Float16* rp = &r16[((size_t)b * N_ + n) * H_ + q * 16];
    f16x8 h0 = *(const f16x8*)hp;
    f16x8 h1 = *(const f16x8*)(hp + 8);
    f16x8 r0 = *(const f16x8*)rp;
    f16x8 r1 = *(const f16x8*)(rp + 8);
#pragma unroll
    for (int i = 0; i < 8; i++) {
      hs[b][q * 16 + i] = h0[i];
      hs[b][q * 16 + 8 + i] = h1[i];
      rs[b][q * 16 + i] = r0[i];
      rs[b][q * 16 + 8 + i] = r1[i];
    }
  }
  __syncthreads();
#pragma unroll
  for (int nt = 0; nt < 4; nt++) {
    const int o = nt * 16 + fm;
    const float bias = bias_s[o];
    const f32x4 v = acc[nt];
#pragma unroll
    for (int j = 0; j < 4; j++) {
      const int b = wave * 16 + fq * 4 + j;
      float hc = tanhf(v[j] + bias);
      float rv = (float)rs[b][o];
      float hv = (float)hs[b][o];
      hs[b][o] = (_Float16)(rv * hv + (1.0f - rv) * hc);
    }
  }
  __syncthreads();
  {
    const int b = tid >> 2, q = tid & 3;
    _Float16* hp = &h16[((size_t)b * N_ + n) * H_ + q * 16];
    f16x8 h0, h1;
#pragma unroll
    for (int i = 0; i < 8; i++) {
      h0[i] = hs[b][q * 16 + i];
      h1[i] = hs[b][q * 16 + 8 + i];
    }
    *(f16x8*)hp = h0;
    *(f16x8*)(hp + 8) = h1;
    if (donext) {
      _Float16* xp = &X0out[(size_t)n * BC_ + b * 65 + 1 + q * 16];
      *(f16x8*)xp = h0;
      *(f16x8*)(xp + 8) = h1;
      if (tid < 64) {
        float sv = src[((size_t)tid * T_ + (t + 1)) * N_ + n];
        X0out[(size_t)n * BC_ + tid * 65] = (_Float16)sv;
      }
    }
  }
}

// ---------------------------------------------------------------------------
// LN(h) + conv, one thread per (b,n).  h fp16.
__global__ __launch_bounds__(256) void k_final(const _Float16* __restrict__ h16,
                                               const float* __restrict__ out_lng,
                                               const float* __restrict__ out_lnb,
                                               const float* __restrict__ conv_w,
                                               const float* __restrict__ conv_b,
                                               float* __restrict__ out) {
  const int b = blockIdx.x >> 2;
  const int n = (blockIdx.x & 3) * 256 + threadIdx.x;
  __shared__ float cw[12][64];
  __shared__ float cb[12];
  __shared__ float lgs[64], lbs[64];
  for (int idx = threadIdx.x; idx < 12 * 64; idx += 256) cw[idx >> 6][idx & 63] = conv_w[idx];
  if (threadIdx.x < 12) cb[threadIdx.x] = conv_b[threadIdx.x];
  if (threadIdx.x < 64) { lgs[threadIdx.x] = out_lng[threadIdx.x]; lbs[threadIdx.x] = out_lnb[threadIdx.x]; }
  __syncthreads();
  const _Float16* hp = &h16[((size_t)b * N_ + n) * H_];
  float hv[64];
  float mean = 0.f;
#pragma unroll
  for (int i8 = 0; i8 < 8; i8++) {
    f16x8 v = *(const f16x8*)&hp[i8 * 8];
#pragma unroll
    for (int j = 0; j < 8; j++) { hv[i8 * 8 + j] = (float)v[j]; mean += hv[i8 * 8 + j]; }
  }
  mean *= (1.0f / H_);
  float var = 0.f;
#pragma unroll
  for (int i = 0; i < 64; i++) { float d = hv[i] - mean; var += d * d; }
  var *= (1.0f / H_);
  const float rs = rsqrtf(var + EPS_);
  float y[64];
#pragma unroll
  for (int i = 0; i < 64; i++)
    y[i] = (hv[i] - mean) * rs * lgs[i] + lbs[i];
#pragma unroll
  for (int o = 0; o < 12; o++) {
    float acc = cb[o];
#pragma unroll
    for (int i = 0; i < 64; i++) acc = fmaf(y[i], cw[o][i], acc);
    out[((size_t)b * 12 + o) * N_ + n] = acc;
  }
}

// ---------------------------------------------------------------------------
extern "C" void kernel_launch(void* const* d_in, const int* in_sizes, int n_in,
                              void* d_out, int out_size, void* d_ws, size_t ws_size,
                              hipStream_t stream) {
  const float* src      = (const float*)d_in[0];
  const float* node_emb = (const float*)d_in[1];
  const float* time_emb = (const float*)d_in[2];
  const float* gate_wp  = (const float*)d_in[3];
  const float* gate_bp  = (const float*)d_in[4];
  const float* gate_lng = (const float*)d_in[5];
  const float* gate_lnb = (const float*)d_in[6];
  const float* upd_wp   = (const float*)d_in[7];
  const float* upd_bp   = (const float*)d_in[8];
  const float* upd_lng  = (const float*)d_in[9];
  const float* upd_lnb  = (const float*)d_in[10];
  const float* out_lng  = (const float*)d_in[11];
  const float* out_lnb  = (const float*)d_in[12];
  const float* conv_w   = (const float*)d_in[13];
  const float* conv_b   = (const float*)d_in[14];
  float* out = (float*)d_out;

  constexpr size_t SZ_H16 = (size_t)B_ * N_ * H_ / 2;    // h fp16
  constexpr size_t SZ_R   = SZ_H16;                      // r fp16
  constexpr size_t SZ_T   = (size_t)NPAD_ * 1024 / 2;    // Xt (padded): 2,162,688
  constexpr size_t SZ_ROW = (size_t)N_ * BC_ / 2;        // row-major fp16: 2,129,920
  constexpr size_t SZ_WT  = (size_t)N_ * OG_ * KP_ / 2;  // 14,680,064 (WtU aliases 1st half)
  constexpr size_t SZ_WCG = (size_t)COLG_ * 16 / 2;
  constexpr size_t SZ_WCU = (size_t)COLU_ * 16 / 2;
  constexpr size_t SZ_S   = (size_t)N_ * N_ / 2;         // one fp16 NxN

  float* ws = (float*)d_ws;
  size_t off = 0;
  float* h16F   = ws + off; off += SZ_H16;
  float* r16F   = ws + off; off += SZ_R;
  float* XtF    = ws + off; off += SZ_T;
  float* X0F    = ws + off; off += SZ_ROW;
  float* y1F    = ws + off; off += SZ_ROW;
  float* y2F    = ws + off; off += SZ_ROW;
  float* WtF    = ws + off; off += SZ_WT;
  float* wcgF   = ws + off; off += SZ_WCG;
  float* wcuF   = ws + off; off += SZ_WCU;
  float* supGF  = ws + off; off += 2 * SZ_S;   // double-buffered
  float* supUF  = ws + off; off += 2 * SZ_S;
  float* supGTF = ws + off; off += SZ_S;
  float* supUTF = ws + off; off += SZ_S;
  float* s2GF   = ws + off; off += 2 * SZ_S;
  float* s2UF   = ws + off; off += 2 * SZ_S;
  float* eg_all  = ws + off; off += (size_t)T_ * NE_;
  float* egT_all = ws + off; off += (size_t)T_ * NE_;
  float* eu_all  = ws + off; off += (size_t)T_ * NE_;
  float* euT_all = ws + off; off += (size_t)T_ * NE_;
  if (ws_size < off * sizeof(float)) return;   // ~135 MB

  _Float16* h16   = (_Float16*)h16F;
  _Float16* r16   = (_Float16*)r16F;
  _Float16* Xt    = (_Float16*)XtF;
  _Float16* X0row = (_Float16*)X0F;
  _Float16* y1row = (_Float16*)y1F;
  _Float16* y2row = (_Float16*)y2F;
  _Float16* WtG   = (_Float16*)WtF;
  _Float16* WtU   = (_Float16*)WtF;
  _Float16* wpCg  = (_Float16*)wcgF;
  _Float16* wpCu  = (_Float16*)wcuF;
  _Float16* supG  = (_Float16*)supGF;
  _Float16* supU  = (_Float16*)supUF;
  _Float16* supGT = (_Float16*)supGTF;
  _Float16* supUT = (_Float16*)supUTF;
  _Float16* s2G   = (_Float16*)s2GF;
  _Float16* s2U   = (_Float16*)s2UF;
  const size_t SB = (size_t)N_ * N_;

  hipMemsetAsync(h16, 0, SZ_H16 * sizeof(float), stream);
  k_pre0<<<2 * KP_ + 48, 256, 0, stream>>>(gate_wp, upd_wp, wpCg, wpCu,
                                           node_emb, time_emb,
                                           gate_lng, gate_lnb, upd_lng, upd_lnb,
                                           eg_all, egT_all, eu_all, euT_all);
  k_pro<<<3072, 256, 0, stream>>>(egT_all, euT_all, src, supG, supU, Xt, X0row);
  k_proT<<<512, 256, 0, stream>>>(supG, supU, supGT, supUT);
  k_pro2<<<256, 256, 0, stream>>>(supG, supGT, supU, supUT, s2G, s2U);

  for (int t = 0; t < T_; t++) {
    const int cur = t & 1, nxt = (t + 1) & 1;
    _Float16* supG_t  = supG + (size_t)cur * SB;
    _Float16* supG_nx = supG + (size_t)nxt * SB;
    _Float16* supU_t  = supU + (size_t)cur * SB;
    _Float16* supU_nx = supU + (size_t)nxt * SB;
    _Float16* s2G_t   = s2G + (size_t)cur * SB;
    _Float16* s2G_nx  = s2G + (size_t)nxt * SB;
    _Float16* s2U_t   = s2U + (size_t)cur * SB;
    _Float16* s2U_nx  = s2U + (size_t)nxt * SB;
    const float* eg_t = eg_all + (size_t)t * NE_;
    const float* eu_t = eu_all + (size_t)t * NE_;
    const int more = (t < T_ - 1) ? 1 : 0;
    const int tn = more ? t + 1 : t;

    k_ga<<<more ? 3024 : 976, 256, 0, stream>>>(
        supG_t, s2G_t, Xt, y1row, y2row, eg_t, wpCg, WtG,
        egT_all + (size_t)tn * NE_, euT_all + (size_t)tn * NE_, supG_nx, supU_nx);
    k_cgT<<<more ? 1536 : 1024, 256, 0, stream>>>(
        eg_t, X0row, y1row, y2row, WtG, gate_bp, h16, src, t, r16, X0row,
        supG_nx, supU_nx, supGT, supUT);
    k_tr<<<1040, 256, 0, stream>>>(X0row, Xt);        // upd X -> Xt
    k_gu<<<more ? 1008 : 752, 256, 0, stream>>>(
        supU_t, s2U_t, Xt, y1row, y2row, eu_t, wpCu, WtU,
        supG_nx, supGT, supU_nx, supUT, s2G_nx, s2U_nx);
    k_cu<<<N_, 256, 0, stream>>>(eu_t, X0row, y1row, y2row, WtU, upd_bp, r16,
                                 src, t, more, h16, X0row);
    if (more) k_tr<<<1040, 256, 0, stream>>>(X0row, Xt);   // next gate X -> Xt
  }
  k_final<<<B_ * N_ / 256, 256, 0, stream>>>(h16, out_lng, out_lnb, conv_w, conv_b, out);
}